// Round 7
// baseline (299.904 us; speedup 1.0000x reference)
//
#include <hip/hip_runtime.h>
#include <float.h>

// Problem constants
#define NBATCH 32
#define NCHAN  256
#define NHW    1024          // 32*32
#define NTOK   32768         // NBATCH * NHW
#define NK     8192          // codebook size
#define ND     256           // token dim
#define ZELEMS 8388608       // NBATCH*NCHAN*NHW
#define OUT_LOSS 8388608
#define OUT_IDX  8388611
#define MARGIN   1.2e-4f     // bf16 pre-screen err + fp32 quant tie window + slack

typedef short bf16x8  __attribute__((ext_vector_type(8)));
typedef float f32x4   __attribute__((ext_vector_type(4)));
typedef float f32x16  __attribute__((ext_vector_type(16)));

__device__ __forceinline__ unsigned short f2bf(float f) {   // RNE
    unsigned int u = __float_as_uint(f);
    u += 0x7FFFu + ((u >> 16) & 1u);
    return (unsigned short)(u >> 16);
}

__device__ __forceinline__ float embed8(float x, int code) {
    return __int_as_float((__float_as_int(x) & 0xFFFFFF00) | code);
}

// ws layout (floats):
//  [0] loss accumulator, [1] block counter (int)
//  [64 .. 64+8192)        en[k] = ||e_k||^2
//  [8256 .. +32768)       idxw (int) per token
//  [41024 .. +4194304)    part2: float2 [32 slot][32768 tok] (8 MB used)
//  then                   Epre: bf16 E [64 tile][8 kc][4 plane][128 row][16B] (4 MB)
// Zpre (bf16 z, [256 mb][8 kc][4 plane][128 tok][16B], 16 MB) lives in
// d_out[0..16MB) until k_gather rewrites it.  plane = ks*2+lhi (K-subchunk).

// ---------------------------------------------------------------- casts
// blocks [0,1024): E -> Epre (+ en, acc/counter init); [1024,3072): z -> Zpre
__global__ __launch_bounds__(256) void k_cast(const float* __restrict__ zg,
                                              const float* __restrict__ E,
                                              unsigned short* __restrict__ Epre,
                                              unsigned short* __restrict__ Zpre,
                                              float* __restrict__ en,
                                              float* __restrict__ acc,
                                              int* __restrict__ counter) {
    __shared__ unsigned short buf[128][34];
    const int t = threadIdx.x;
    if (blockIdx.x < 1024) {
        int g = blockIdx.x * 256 + t;                // 8192 codes * 32 chunks
        int code = g >> 5, c16 = g & 31;             // c16: 16B chunk = 8 channels
        int kc = c16 >> 2, ks = (c16 >> 1) & 1, lhi = c16 & 1;
        const float4* E4 = (const float4*)(E + code * ND + c16 * 8);
        float4 a = E4[0], b = E4[1];
        float s = a.x*a.x + a.y*a.y + a.z*a.z + a.w*a.w
                + b.x*b.x + b.y*b.y + b.z*b.z + b.w*b.w;
        #pragma unroll
        for (int off = 1; off < 32; off <<= 1) s += __shfl_xor(s, off, 64);
        if ((t & 31) == 0) en[code] = s;
        unsigned int u[4];
        u[0] = (unsigned int)f2bf(a.x) | ((unsigned int)f2bf(a.y) << 16);
        u[1] = (unsigned int)f2bf(a.z) | ((unsigned int)f2bf(a.w) << 16);
        u[2] = (unsigned int)f2bf(b.x) | ((unsigned int)f2bf(b.y) << 16);
        u[3] = (unsigned int)f2bf(b.z) | ((unsigned int)f2bf(b.w) << 16);
        *(uint4*)((char*)Epre + (size_t)(code >> 7) * 65536 + kc * 8192
                  + (ks * 2 + lhi) * 2048 + (code & 127) * 16) =
            make_uint4(u[0], u[1], u[2], u[3]);
        if (blockIdx.x == 0 && t == 0) { acc[0] = 0.0f; counter[0] = 0; }
    } else {
        int bi = blockIdx.x - 1024;           // 32 b * 8 kc * 8 hwt
        int b = bi >> 6, kc = (bi >> 3) & 7, hwt = bi & 7;
        int c0 = kc * 32, hw0 = hwt * 128;
        #pragma unroll
        for (int r = 0; r < 4; ++r) {
            int idx = r * 256 + t;
            int c = idx >> 5, q = idx & 31;
            float4 v = *(const float4*)&zg[(b * 256 + c0 + c) * 1024 + hw0 + q * 4];
            buf[q * 4 + 0][c] = f2bf(v.x);
            buf[q * 4 + 1][c] = f2bf(v.y);
            buf[q * 4 + 2][c] = f2bf(v.z);
            buf[q * 4 + 3][c] = f2bf(v.w);
        }
        __syncthreads();
        int tok = t >> 1, ks = t & 1;
        char* base = (char*)Zpre + (size_t)((b * 8 + hwt) * 8 + kc) * 8192;
        #pragma unroll
        for (int lhi = 0; lhi < 2; ++lhi) {
            unsigned int u[4];
            #pragma unroll
            for (int k = 0; k < 4; ++k) {
                int cc = ks * 16 + lhi * 8 + 2 * k;
                u[k] = (unsigned int)buf[tok][cc] | ((unsigned int)buf[tok][cc + 1] << 16);
            }
            *(uint4*)(base + (ks * 2 + lhi) * 2048 + tok * 16) =
                make_uint4(u[0], u[1], u[2], u[3]);
        }
    }
}

// ---------------------------------------------------------------- kernel 2
// MFMA pre-screen, D[code][token], 32x32x16 bf16.
// Block = 256 codes x 128 tokens.
// R7: Z OUT OF LDS. Z fragments are wave-private -> load global->VGPR with
// 1-kc lookahead ping-pong (R2's free-running style; Z is L2-resident,
// 1.05 GB total). E (4-way wave reuse) stays LDS-staged via global_load_lds,
// 3-buffer rolling window, stage-ahead-2. LDS traffic/CU drops 18.4->12 MB
// (below the 58us MFMA floor) and the per-kc barrier needs NO drain:
// E-gll completion is guaranteed by in-order vmcnt retirement (the Z-load
// waits the compiler must insert retire older E-glls); explicit counted
// vmcnt(12) at each barrier as architectural safety. Z loads and E-glls
// flow freely ACROSS barriers; ds_read(ea) overlaps MFMA + Z latency.
// vmcnt ledger (order: [E0 E1 Z0 | sync] then per kc: E_{kc+2}, Z_{kc+1}):
//   bd1: after E1: Z0,E2,Z1 in flight at most -> vmcnt(8) is safe (E1 was
//        drained by prologue __syncthreads anyway); bd2..6: after E_kc:
//        Z_{kc-1}+E_{kc+1}+Z_kc = 12 -> vmcnt(12); bd7: after E7: Z6+Z7=8.
// Overwrite safety: buffer (kc+2)%3 overwritten at iter kc held E_{kc-1},
// whose ds_reads were consumed by iter kc-1 MFMAs (compiler lgkm waits)
// before any wave passed barrier kc. No explicit lgkmcnt needed.
__global__ __launch_bounds__(256, 2) void k_dist(const unsigned short* __restrict__ Epre,
                                                 const unsigned short* __restrict__ Zpre,
                                                 const float* __restrict__ en,
                                                 float2* __restrict__ part2) {
    __shared__ __align__(16) char Elds[3][16384];   // 3buf: 2 subtile x 4 plane x 128 row x 16B
    __shared__ float2 red[2][128];
    __shared__ float en_s[256];

    const int t    = threadIdx.x;
    const int kbb2 = blockIdx.x;               // 0..31 (256 codes each)
    const int mb   = blockIdx.y;               // 0..255
    const int n0   = mb * 128;
    const int w    = t >> 6, lane = t & 63;
    const int l31  = lane & 31, lhi = lane >> 5;
    const int wm   = w >> 1, wn = w & 1;       // wave tile: 128 codes x 64 tokens

    const char* Esrc = (const char*)Epre + (size_t)kbb2 * 131072;  // 2 tiles
    const char* Zsrc = (const char*)Zpre + (size_t)mb * 65536;

    auto STAGE_E = [&](int bb, int kc) {
        #pragma unroll
        for (int s2 = 0; s2 < 2; ++s2)
            #pragma unroll
            for (int h = 0; h < 2; ++h)
                __builtin_amdgcn_global_load_lds(
                    (const unsigned int*)(Esrc + (size_t)s2 * 65536 + kc * 8192 + h * 4096 + t * 16),
                    (unsigned int*)&Elds[bb][s2 * 8192 + h * 4096 + t * 16], 16, 0, 0);
    };

    bf16x8 zbR[2][2][2];                       // [set][j][ks] global->reg ping-pong
    const char* Zp = Zsrc + lhi * 2048 + (wn * 64 + l31) * 16;
    auto LOADZ = [&](int set, int kc) {
        const char* p = Zp + kc * 8192;
        #pragma unroll
        for (int j = 0; j < 2; ++j)
            #pragma unroll
            for (int ks = 0; ks < 2; ++ks)
                zbR[set][j][ks] = *(const bf16x8*)(p + ks * 4096 + j * 512);
    };

    f32x16 acc[4][2];                          // [i][j]
    #pragma unroll
    for (int i = 0; i < 4; ++i)
        #pragma unroll
        for (int j = 0; j < 2; ++j) acc[i][j] = (f32x16)0.0f;

    // prologue: E0,E1 staged; Z0 in regs; en -> LDS; one full sync
    STAGE_E(0, 0);
    STAGE_E(1, 1);
    LOADZ(0, 0);
    en_s[t] = en[kbb2 * 256 + t];
    __syncthreads();

    #pragma unroll
    for (int kc = 0; kc < 8; ++kc) {
        const int pp = kc & 1, eb = kc % 3;
        if (kc == 1 || kc == 7) {
            asm volatile("s_waitcnt vmcnt(8)" ::: "memory");
            __builtin_amdgcn_s_barrier();
        } else if (kc >= 2) {                  // kc = 2..6
            asm volatile("s_waitcnt vmcnt(12)" ::: "memory");
            __builtin_amdgcn_s_barrier();
        }
        if (kc < 6) STAGE_E((kc + 2) % 3, kc + 2);
        if (kc < 7) LOADZ(pp ^ 1, kc + 1);

        const char* Eb = &Elds[eb][0] + wm * 8192 + lhi * 2048 + l31 * 16;
        bf16x8 ea[4][2];
        #pragma unroll
        for (int i = 0; i < 4; ++i)
            #pragma unroll
            for (int ks = 0; ks < 2; ++ks)
                ea[i][ks] = *(const bf16x8*)(Eb + ks * 4096 + i * 512);

        __builtin_amdgcn_s_setprio(1);
        #pragma unroll
        for (int ks = 0; ks < 2; ++ks)
            #pragma unroll
            for (int i = 0; i < 4; ++i)
                #pragma unroll
                for (int j = 0; j < 2; ++j)
                    acc[i][j] = __builtin_amdgcn_mfma_f32_32x32x16_bf16(
                        ea[i][ks], zbR[pp][j][ks], acc[i][j], 0, 0, 0);
        __builtin_amdgcn_s_setprio(0);
    }

    __syncthreads();                           // full drain before epilogue

    // ---- epilogue: per-token top-2 smallest s = en - 2*dot, 8-bit embed ----
    // 4 independent chains (per i) for ILP, merged pairwise at the end.
    float v1[2][4], v2[2][4];
    #pragma unroll
    for (int j = 0; j < 2; ++j)
        #pragma unroll
        for (int i = 0; i < 4; ++i) { v1[j][i] = FLT_MAX; v2[j][i] = FLT_MAX; }
    #pragma unroll
    for (int i = 0; i < 4; ++i) {
        const int cb = wm * 128 + i * 32 + lhi * 4;
        #pragma unroll
        for (int rq = 0; rq < 4; ++rq) {
            f32x4 ev = *(const f32x4*)&en_s[cb + 8 * rq];
            #pragma unroll
            for (int rr = 0; rr < 4; ++rr) {
                const int r = rq * 4 + rr;
                const int code = cb + 8 * rq + rr;       // 0..255 local
                #pragma unroll
                for (int j = 0; j < 2; ++j) {
                    float s  = fmaf(-2.0f, acc[i][j][r], ev[rr]);
                    float se = embed8(s, code);
                    v2[j][i] = __builtin_amdgcn_fmed3f(se, v1[j][i], v2[j][i]);
                    v1[j][i] = fminf(v1[j][i], se);
                }
            }
        }
    }
    // merge 4 sorted pairs -> 1 (per j): (lo,hi) merge = min/max/min/min
    float m1[2], m2[2];
    #pragma unroll
    for (int j = 0; j < 2; ++j) {
        float a1 = fminf(v1[j][0], v1[j][1]);
        float ah = fmaxf(v1[j][0], v1[j][1]);
        float a2 = fminf(ah, fminf(v2[j][0], v2[j][1]));
        float b1 = fminf(v1[j][2], v1[j][3]);
        float bh = fmaxf(v1[j][2], v1[j][3]);
        float b2 = fminf(bh, fminf(v2[j][2], v2[j][3]));
        m1[j] = fminf(a1, b1);
        m2[j] = fminf(fmaxf(a1, b1), fminf(a2, b2));
    }
    #pragma unroll
    for (int j = 0; j < 2; ++j) {              // merge lhi partner (xor 32)
        float b1 = __shfl_xor(m1[j], 32, 64);
        float b2 = __shfl_xor(m2[j], 32, 64);
        float hi = fmaxf(m1[j], b1);
        m1[j] = fminf(m1[j], b1);
        m2[j] = fminf(fminf(hi, m2[j]), b2);
    }
    if (lane < 32) {
        #pragma unroll
        for (int j = 0; j < 2; ++j)
            red[wm][wn * 64 + j * 32 + l31] = make_float2(m1[j], m2[j]);
    }
    __syncthreads();
    if (t < 128) {
        float2 A = red[0][t], B = red[1][t];
        float g1 = fminf(A.x, B.x);
        float g2 = fminf(fminf(fmaxf(A.x, B.x), A.y), B.y);
        // slot-major: 128 consecutive float2 per block = 1KB full lines
        part2[(size_t)kbb2 * NTOK + n0 + t] = make_float2(g1, g2);
    }
}

// ---------------------------------------------------------------- kernel 3
// Refine: block stages z for 64 tokens into LDS (coalesced); per token-wave,
// mimic reference fp32 rounding:
//   d_q(k) = fl32( z2f - fl32(2*<z,e_k>_fp64) ), argmin, first-index ties.
// 32 slots per token (256 codes each), 8-bit embedded local index.
__global__ __launch_bounds__(256) void k_refine(const float* __restrict__ zg,
                                                const float* __restrict__ E,
                                                const float2* __restrict__ part2,
                                                int* __restrict__ idxw,
                                                float* __restrict__ outF) {
    __shared__ float Zs[256 * 65];             // [c][tok] stride 65 (bank-clean)
    const int t = threadIdx.x;
    const int n0 = blockIdx.x * 64;
    const int b = n0 >> 10, hw0 = n0 & 1023;

    #pragma unroll
    for (int r = 0; r < 16; ++r) {
        int li = r * 256 + t;
        int c = li >> 4, q = li & 15;
        float4 v = *(const float4*)&zg[(b * 256 + c) * 1024 + hw0 + q * 4];
        Zs[c * 65 + q * 4 + 0] = v.x;
        Zs[c * 65 + q * 4 + 1] = v.y;
        Zs[c * 65 + q * 4 + 2] = v.z;
        Zs[c * 65 + q * 4 + 3] = v.w;
    }
    __syncthreads();

    const int w = t >> 6, l = t & 63;
    for (int it = 0; it < 16; ++it) {
        const int tokl = w * 16 + it;
        const int n = n0 + tokl;

        float zreg[4];
        #pragma unroll
        for (int j = 0; j < 4; ++j) zreg[j] = Zs[(64 * j + l) * 65 + tokl];

        double z2 = 0.0;
        #pragma unroll
        for (int j = 0; j < 4; ++j) z2 += (double)zreg[j] * (double)zreg[j];
        #pragma unroll
        for (int m = 1; m < 64; m <<= 1) z2 += __shfl_xor(z2, m, 64);
        const float z2f = (float)z2;

        float2 p = make_float2(FLT_MAX, FLT_MAX);
        if (l < 32) p = part2[(size_t)l * NTOK + n];   // slot-major, 32 slots
        int code1 = (l << 8) | (__float_as_int(p.x) & 0xFF);
        int code2 = (l << 8) | (__float_as_int(p.y) & 0xFF);

        float vmin = p.x;
        #pragma unroll
        for (int m = 1; m < 64; m <<= 1) vmin = fminf(vmin, __shfl_xor(vmin, m, 64));
        const float thr = vmin + MARGIN;

        unsigned long long m1 = __ballot(p.x <= thr);
        unsigned long long m2 = __ballot(p.y <= thr);

        float bdq = FLT_MAX; int bidx = 0x7fffffff;
        #pragma unroll
        for (int pass = 0; pass < 2; ++pass) {
            unsigned long long mm = pass ? m2 : m1;
            int ibits = pass ? code2 : code1;
            while (mm) {
                int src = __ffsll(mm) - 1; mm &= mm - 1;
                int cidx = __shfl(ibits, src, 64);
                const float* erow = E + cidx * ND;
                double g = (double)zreg[0] * (double)erow[l]
                         + (double)zreg[1] * (double)erow[64 + l]
                         + (double)zreg[2] * (double)erow[128 + l]
                         + (double)zreg[3] * (double)erow[192 + l];
                #pragma unroll
                for (int mk = 1; mk < 64; mk <<= 1) g += __shfl_xor(g, mk, 64);
                float c  = (float)(2.0 * g);
                float dq = z2f - c;
                if (dq < bdq || (dq == bdq && cidx < bidx)) { bdq = dq; bidx = cidx; }
            }
        }
        if (l == 0) { idxw[n] = bidx; outF[OUT_IDX + n] = (float)bidx; }
    }
}

// ---------------------------------------------------------------- kernel 4
// Gather via LDS-staged E rows (coalesced 1KB row loads, XOR-swizzled),
// fused loss accumulation + last-block loss finalization.
__global__ __launch_bounds__(256) void k_gather(const float* __restrict__ E,
                                                const float* __restrict__ zg,
                                                const int* __restrict__ idxw,
                                                float* __restrict__ out,
                                                float* __restrict__ acc,
                                                int* __restrict__ counter) {
    __shared__ __align__(16) float Es[64 * 256];   // 64 rows x 1KB
    __shared__ int sidx[64];
    __shared__ float wred[4];
    const int t = threadIdx.x;
    const int b = blockIdx.x >> 4, ht = blockIdx.x & 15;

    if (t < 64) sidx[t] = idxw[b * 1024 + ht * 64 + t];
    __syncthreads();
    const float4* E4 = (const float4*)E;
    #pragma unroll
    for (int r = 0; r < 16; ++r) {
        int li = r * 256 + t;
        int row = li >> 6, slot = li & 63;
        float4 v = E4[(size_t)sidx[row] * 64 + slot];
        *(float4*)&Es[row * 256 + ((slot ^ (row & 15)) * 4)] = v;
    }
    __syncthreads();

    const int hw = t & 63, wv = t >> 6;
    float s = 0.0f;
    #pragma unroll 8
    for (int cc = 0; cc < 64; ++cc) {
        int c = wv * 64 + cc;
        float e = Es[hw * 256 + (((c >> 2) ^ (hw & 15)) * 4) + (c & 3)];
        size_t gi = (size_t)(b * 256 + c) * 1024 + ht * 64 + hw;
        float zv = zg[gi];
        out[gi] = e;
        float d = e - zv;
        s = fmaf(d, d, s);
    }
    #pragma unroll
    for (int off = 32; off > 0; off >>= 1) s += __shfl_down(s, off, 64);
    if ((t & 63) == 0) wred[wv] = s;
    __syncthreads();
    if (t == 0) {
        atomicAdd(acc, wred[0] + wred[1] + wred[2] + wred[3]);
        __threadfence();
        int old = atomicAdd(counter, 1);
        if (old == 511) {
            float total = atomicAdd(acc, 0.0f);   // RMW => device-coherent read
            float mse = total / 8388608.0f;
            out[OUT_LOSS + 0] = 1.25f * mse;
            out[OUT_LOSS + 1] = 0.25f * mse;
            out[OUT_LOSS + 2] = mse;
        }
    }
}

extern "C" void kernel_launch(void* const* d_in, const int* in_sizes, int n_in,
                              void* d_out, int out_size, void* d_ws, size_t ws_size,
                              hipStream_t stream) {
    const float* zg = (const float*)d_in[0];
    const float* E  = (const float*)d_in[1];
    float* out = (float*)d_out;
    float* wsf = (float*)d_ws;
    float*  acc     = wsf;
    int*    counter = (int*)(wsf + 1);
    float*  en      = wsf + 64;
    int*    idxw    = (int*)(wsf + 64 + NK);
    float2* part2   = (float2*)(wsf + 64 + NK + NTOK);            // 8 MB used
    unsigned short* Epre = (unsigned short*)(wsf + 64 + NK + NTOK + 4194304);  // 4 MB
    unsigned short* Zpre = (unsigned short*)d_out;                // 16 MB scratch

    k_cast  <<<3072, 256, 0, stream>>>(zg, E, Epre, Zpre, en, acc, counter);
    k_dist  <<<dim3(32, 256), 256, 0, stream>>>(Epre, Zpre, en, part2);
    k_refine<<<NTOK / 64, 256, 0, stream>>>(zg, E, part2, idxw, out);
    k_gather<<<512, 256, 0, stream>>>(E, zg, idxw, out, acc, counter);
}

// Round 8
// 299.529 us; speedup vs baseline: 1.0013x; 1.0013x over previous
//
#include <hip/hip_runtime.h>
#include <float.h>

// Problem constants
#define NBATCH 32
#define NCHAN  256
#define NHW    1024          // 32*32
#define NTOK   32768         // NBATCH * NHW
#define NK     8192          // codebook size
#define ND     256           // token dim
#define ZELEMS 8388608       // NBATCH*NCHAN*NHW
#define OUT_LOSS 8388608
#define OUT_IDX  8388611
#define MARGIN   1.2e-4f     // bf16 pre-screen err + fp32 quant tie window + slack

typedef short bf16x8  __attribute__((ext_vector_type(8)));
typedef float f32x4   __attribute__((ext_vector_type(4)));
typedef float f32x16  __attribute__((ext_vector_type(16)));

__device__ __forceinline__ unsigned short f2bf(float f) {   // RNE
    unsigned int u = __float_as_uint(f);
    u += 0x7FFFu + ((u >> 16) & 1u);
    return (unsigned short)(u >> 16);
}

__device__ __forceinline__ float embed8(float x, int code) {
    return __int_as_float((__float_as_int(x) & 0xFFFFFF00) | code);
}

// ws layout (floats):
//  [0] loss accumulator, [1] block counter (int)
//  [64 .. 64+8192)        en[k] = ||e_k||^2
//  [8256 .. +32768)       idxw (int) per token
//  [41024 .. +4194304)    part2: float2 [32 slot][32768 tok] (8 MB used)
//  then                   Epre: bf16 E [64 tile][8 kc][4 plane][128 row][16B] (4 MB)
// Zpre (bf16 z, [256 mb][8 kc][4 plane][128 tok][16B], 16 MB) lives in
// d_out[0..16MB) until k_gather rewrites it.  plane = ks*2+lhi (K-subchunk).

// ---------------------------------------------------------------- casts
// blocks [0,1024): E -> Epre (+ en, acc/counter init); [1024,3072): z -> Zpre
__global__ __launch_bounds__(256) void k_cast(const float* __restrict__ zg,
                                              const float* __restrict__ E,
                                              unsigned short* __restrict__ Epre,
                                              unsigned short* __restrict__ Zpre,
                                              float* __restrict__ en,
                                              float* __restrict__ acc,
                                              int* __restrict__ counter) {
    __shared__ unsigned short buf[128][34];
    const int t = threadIdx.x;
    if (blockIdx.x < 1024) {
        int g = blockIdx.x * 256 + t;                // 8192 codes * 32 chunks
        int code = g >> 5, c16 = g & 31;             // c16: 16B chunk = 8 channels
        int kc = c16 >> 2, ks = (c16 >> 1) & 1, lhi = c16 & 1;
        const float4* E4 = (const float4*)(E + code * ND + c16 * 8);
        float4 a = E4[0], b = E4[1];
        float s = a.x*a.x + a.y*a.y + a.z*a.z + a.w*a.w
                + b.x*b.x + b.y*b.y + b.z*b.z + b.w*b.w;
        #pragma unroll
        for (int off = 1; off < 32; off <<= 1) s += __shfl_xor(s, off, 64);
        if ((t & 31) == 0) en[code] = s;
        unsigned int u[4];
        u[0] = (unsigned int)f2bf(a.x) | ((unsigned int)f2bf(a.y) << 16);
        u[1] = (unsigned int)f2bf(a.z) | ((unsigned int)f2bf(a.w) << 16);
        u[2] = (unsigned int)f2bf(b.x) | ((unsigned int)f2bf(b.y) << 16);
        u[3] = (unsigned int)f2bf(b.z) | ((unsigned int)f2bf(b.w) << 16);
        *(uint4*)((char*)Epre + (size_t)(code >> 7) * 65536 + kc * 8192
                  + (ks * 2 + lhi) * 2048 + (code & 127) * 16) =
            make_uint4(u[0], u[1], u[2], u[3]);
        if (blockIdx.x == 0 && t == 0) { acc[0] = 0.0f; counter[0] = 0; }
    } else {
        int bi = blockIdx.x - 1024;           // 32 b * 8 kc * 8 hwt
        int b = bi >> 6, kc = (bi >> 3) & 7, hwt = bi & 7;
        int c0 = kc * 32, hw0 = hwt * 128;
        #pragma unroll
        for (int r = 0; r < 4; ++r) {
            int idx = r * 256 + t;
            int c = idx >> 5, q = idx & 31;
            float4 v = *(const float4*)&zg[(b * 256 + c0 + c) * 1024 + hw0 + q * 4];
            buf[q * 4 + 0][c] = f2bf(v.x);
            buf[q * 4 + 1][c] = f2bf(v.y);
            buf[q * 4 + 2][c] = f2bf(v.z);
            buf[q * 4 + 3][c] = f2bf(v.w);
        }
        __syncthreads();
        int tok = t >> 1, ks = t & 1;
        char* base = (char*)Zpre + (size_t)((b * 8 + hwt) * 8 + kc) * 8192;
        #pragma unroll
        for (int lhi = 0; lhi < 2; ++lhi) {
            unsigned int u[4];
            #pragma unroll
            for (int k = 0; k < 4; ++k) {
                int cc = ks * 16 + lhi * 8 + 2 * k;
                u[k] = (unsigned int)buf[tok][cc] | ((unsigned int)buf[tok][cc + 1] << 16);
            }
            *(uint4*)(base + (ks * 2 + lhi) * 2048 + tok * 16) =
                make_uint4(u[0], u[1], u[2], u[3]);
        }
    }
}

// ---------------------------------------------------------------- kernel 2
// MFMA pre-screen, D[code][token], 32x32x16 bf16.
// R8: SAME 256x128 block tile / LDS layout / 3-buffer counted-vmcnt schedule
// as R4, but 512 THREADS = 8 waves of 64x64 (acc[2][2] = 64 VGPR/wave).
// Why: per-SIMD a 32x32x16 MFMA occupies ~32 cyc (m119: 2495 TF => ~8 cyc/CU
// = 32/SIMD). At 2 waves/SIMD (R4-R7) the pipe can only reach ~33% -- every
// schedule trick was null because TLP, not the schedule, was binding.
// 4 waves/SIMD doubles the interleave at identical traffic/FLOP.
// __launch_bounds__(512,4): 4 waves/EU = 2 blocks/CU (reg budget 128:
// acc 64 + ea/zb 32 + misc ~25 fits).
// vmcnt ledger (3 glls per thread per STAGE at 512 thr): prologue stages
// S0,S1 then __syncthreads drains; iter kc issues S_{kc+2}; at top of kc:
// outstanding = S_kc,S_{kc+1} (6) -> vmcnt(3) retires S_kc; kc=7: vmcnt(0).
// Buffer overwrite safe: buf (kc+2)%3 = (kc-1)%3, whose ds_reads were
// consumed by iter kc-1 MFMAs (compiler lgkm waits) before barrier kc.
__global__ __launch_bounds__(512, 4) void k_dist(const unsigned short* __restrict__ Epre,
                                                 const unsigned short* __restrict__ Zpre,
                                                 const float* __restrict__ en,
                                                 float2* __restrict__ part2) {
    __shared__ __align__(16) char Elds[3][16384];   // 3buf: 2 subtile x 4 plane x 128 row x 16B
    __shared__ __align__(16) char Zlds[3][8192];    // 3buf: 4 plane x 128 tok x 16B
    __shared__ float2 red[4][128];                  // per-wm top2 per token
    __shared__ float en_s[256];

    const int t    = threadIdx.x;
    const int kbb2 = blockIdx.x;               // 0..31 (256 codes each)
    const int mb   = blockIdx.y;               // 0..255
    const int n0   = mb * 128;
    const int w    = t >> 6, lane = t & 63;
    const int l31  = lane & 31, lhi = lane >> 5;
    const int wm   = w >> 1, wn = w & 1;       // wave tile: 64 codes x 64 tokens

    const char* Esrc = (const char*)Epre + (size_t)kbb2 * 131072;  // 2 tiles
    const char* Zsrc = (const char*)Zpre + (size_t)mb * 65536;

    auto STAGE = [&](int bb, int kc) {         // 3 glls per thread (512 thr)
        #pragma unroll
        for (int s2 = 0; s2 < 2; ++s2)
            __builtin_amdgcn_global_load_lds(
                (const unsigned int*)(Esrc + (size_t)s2 * 65536 + kc * 8192 + t * 16),
                (unsigned int*)&Elds[bb][s2 * 8192 + t * 16], 16, 0, 0);
        __builtin_amdgcn_global_load_lds(
            (const unsigned int*)(Zsrc + kc * 8192 + t * 16),
            (unsigned int*)&Zlds[bb][t * 16], 16, 0, 0);
    };

    f32x16 acc[2][2];                          // [i][j]
    #pragma unroll
    for (int i = 0; i < 2; ++i)
        #pragma unroll
        for (int j = 0; j < 2; ++j) acc[i][j] = (f32x16)0.0f;

    // prologue: stage kc=0,1; en -> LDS; one full drain
    STAGE(0, 0);
    STAGE(1, 1);
    if (t < 256) en_s[t] = en[kbb2 * 256 + t];
    __syncthreads();

    const int eoff = (wm >> 1) * 8192 + (wm & 1) * 1024 + lhi * 2048 + l31 * 16;
    const int zoff = lhi * 2048 + (wn * 64 + l31) * 16;

    #pragma unroll
    for (int kc = 0; kc < 8; ++kc) {
        const int pp = kc % 3;
        if (kc >= 1) {
            if (kc < 7) { asm volatile("s_waitcnt vmcnt(3)" ::: "memory"); }
            else        { asm volatile("s_waitcnt vmcnt(0)" ::: "memory"); }
            __builtin_amdgcn_s_barrier();
        }
        if (kc < 6) STAGE((kc + 2) % 3, kc + 2);

        const char* Eb = &Elds[pp][0] + eoff;
        const char* Zb = &Zlds[pp][0] + zoff;
        bf16x8 ea[2][2], zb[2][2];
        #pragma unroll
        for (int i = 0; i < 2; ++i)
            #pragma unroll
            for (int ks = 0; ks < 2; ++ks)
                ea[i][ks] = *(const bf16x8*)(Eb + ks * 4096 + i * 512);
        #pragma unroll
        for (int j = 0; j < 2; ++j)
            #pragma unroll
            for (int ks = 0; ks < 2; ++ks)
                zb[j][ks] = *(const bf16x8*)(Zb + ks * 4096 + j * 512);

        __builtin_amdgcn_s_setprio(1);
        #pragma unroll
        for (int ks = 0; ks < 2; ++ks)
            #pragma unroll
            for (int i = 0; i < 2; ++i)
                #pragma unroll
                for (int j = 0; j < 2; ++j)
                    acc[i][j] = __builtin_amdgcn_mfma_f32_32x32x16_bf16(
                        ea[i][ks], zb[j][ks], acc[i][j], 0, 0, 0);
        __builtin_amdgcn_s_setprio(0);
    }

    __syncthreads();                           // full drain before epilogue

    // ---- epilogue: per-token top-2 smallest s = en - 2*dot, 8-bit embed ----
    // per lane: 2 tokens (j), 32 codes each (2i x 16r); 2 chains per token.
    float v1[2][2], v2[2][2];                  // [j][i]
    #pragma unroll
    for (int j = 0; j < 2; ++j)
        #pragma unroll
        for (int i = 0; i < 2; ++i) { v1[j][i] = FLT_MAX; v2[j][i] = FLT_MAX; }
    #pragma unroll
    for (int i = 0; i < 2; ++i) {
        const int cb = wm * 64 + i * 32 + lhi * 4;
        #pragma unroll
        for (int rq = 0; rq < 4; ++rq) {
            f32x4 ev = *(const f32x4*)&en_s[cb + 8 * rq];
            #pragma unroll
            for (int rr = 0; rr < 4; ++rr) {
                const int r = rq * 4 + rr;
                const int code = cb + 8 * rq + rr;       // 0..255 local
                #pragma unroll
                for (int j = 0; j < 2; ++j) {
                    float s  = fmaf(-2.0f, acc[i][j][r], ev[rr]);
                    float se = embed8(s, code);
                    v2[j][i] = __builtin_amdgcn_fmed3f(se, v1[j][i], v2[j][i]);
                    v1[j][i] = fminf(v1[j][i], se);
                }
            }
        }
    }
    float m1[2], m2[2];
    #pragma unroll
    for (int j = 0; j < 2; ++j) {              // merge the 2 i-chains
        float a1 = fminf(v1[j][0], v1[j][1]);
        float ah = fmaxf(v1[j][0], v1[j][1]);
        m1[j] = a1;
        m2[j] = fminf(ah, fminf(v2[j][0], v2[j][1]));
    }
    #pragma unroll
    for (int j = 0; j < 2; ++j) {              // merge lhi partner (xor 32)
        float b1 = __shfl_xor(m1[j], 32, 64);
        float b2 = __shfl_xor(m2[j], 32, 64);
        float hi = fmaxf(m1[j], b1);
        m1[j] = fminf(m1[j], b1);
        m2[j] = fminf(fminf(hi, m2[j]), b2);
    }
    if (lane < 32) {
        #pragma unroll
        for (int j = 0; j < 2; ++j)
            red[wm][wn * 64 + j * 32 + l31] = make_float2(m1[j], m2[j]);
    }
    __syncthreads();
    if (t < 128) {                             // merge 4 wm pairs -> final top2
        float2 A = red[0][t], B = red[1][t], C = red[2][t], D = red[3][t];
        float ab1 = fminf(A.x, B.x);
        float ab2 = fminf(fmaxf(A.x, B.x), fminf(A.y, B.y));
        float cd1 = fminf(C.x, D.x);
        float cd2 = fminf(fmaxf(C.x, D.x), fminf(C.y, D.y));
        float g1 = fminf(ab1, cd1);
        float g2 = fminf(fmaxf(ab1, cd1), fminf(ab2, cd2));
        // slot-major: 128 consecutive float2 per block = 1KB full lines
        part2[(size_t)kbb2 * NTOK + n0 + t] = make_float2(g1, g2);
    }
}

// ---------------------------------------------------------------- kernel 3
// Refine: block stages z for 64 tokens into LDS (coalesced); per token-wave,
// mimic reference fp32 rounding:
//   d_q(k) = fl32( z2f - fl32(2*<z,e_k>_fp64) ), argmin, first-index ties.
// 32 slots per token (256 codes each), 8-bit embedded local index.
__global__ __launch_bounds__(256) void k_refine(const float* __restrict__ zg,
                                                const float* __restrict__ E,
                                                const float2* __restrict__ part2,
                                                int* __restrict__ idxw,
                                                float* __restrict__ outF) {
    __shared__ float Zs[256 * 65];             // [c][tok] stride 65 (bank-clean)
    const int t = threadIdx.x;
    const int n0 = blockIdx.x * 64;
    const int b = n0 >> 10, hw0 = n0 & 1023;

    #pragma unroll
    for (int r = 0; r < 16; ++r) {
        int li = r * 256 + t;
        int c = li >> 4, q = li & 15;
        float4 v = *(const float4*)&zg[(b * 256 + c) * 1024 + hw0 + q * 4];
        Zs[c * 65 + q * 4 + 0] = v.x;
        Zs[c * 65 + q * 4 + 1] = v.y;
        Zs[c * 65 + q * 4 + 2] = v.z;
        Zs[c * 65 + q * 4 + 3] = v.w;
    }
    __syncthreads();

    const int w = t >> 6, l = t & 63;
    for (int it = 0; it < 16; ++it) {
        const int tokl = w * 16 + it;
        const int n = n0 + tokl;

        float zreg[4];
        #pragma unroll
        for (int j = 0; j < 4; ++j) zreg[j] = Zs[(64 * j + l) * 65 + tokl];

        double z2 = 0.0;
        #pragma unroll
        for (int j = 0; j < 4; ++j) z2 += (double)zreg[j] * (double)zreg[j];
        #pragma unroll
        for (int m = 1; m < 64; m <<= 1) z2 += __shfl_xor(z2, m, 64);
        const float z2f = (float)z2;

        float2 p = make_float2(FLT_MAX, FLT_MAX);
        if (l < 32) p = part2[(size_t)l * NTOK + n];   // slot-major, 32 slots
        int code1 = (l << 8) | (__float_as_int(p.x) & 0xFF);
        int code2 = (l << 8) | (__float_as_int(p.y) & 0xFF);

        float vmin = p.x;
        #pragma unroll
        for (int m = 1; m < 64; m <<= 1) vmin = fminf(vmin, __shfl_xor(vmin, m, 64));
        const float thr = vmin + MARGIN;

        unsigned long long m1 = __ballot(p.x <= thr);
        unsigned long long m2 = __ballot(p.y <= thr);

        float bdq = FLT_MAX; int bidx = 0x7fffffff;
        #pragma unroll
        for (int pass = 0; pass < 2; ++pass) {
            unsigned long long mm = pass ? m2 : m1;
            int ibits = pass ? code2 : code1;
            while (mm) {
                int src = __ffsll(mm) - 1; mm &= mm - 1;
                int cidx = __shfl(ibits, src, 64);
                const float* erow = E + cidx * ND;
                double g = (double)zreg[0] * (double)erow[l]
                         + (double)zreg[1] * (double)erow[64 + l]
                         + (double)zreg[2] * (double)erow[128 + l]
                         + (double)zreg[3] * (double)erow[192 + l];
                #pragma unroll
                for (int mk = 1; mk < 64; mk <<= 1) g += __shfl_xor(g, mk, 64);
                float c  = (float)(2.0 * g);
                float dq = z2f - c;
                if (dq < bdq || (dq == bdq && cidx < bidx)) { bdq = dq; bidx = cidx; }
            }
        }
        if (l == 0) { idxw[n] = bidx; outF[OUT_IDX + n] = (float)bidx; }
    }
}

// ---------------------------------------------------------------- kernel 4
// Gather via LDS-staged E rows (coalesced 1KB row loads, XOR-swizzled),
// fused loss accumulation + last-block loss finalization.
__global__ __launch_bounds__(256) void k_gather(const float* __restrict__ E,
                                                const float* __restrict__ zg,
                                                const int* __restrict__ idxw,
                                                float* __restrict__ out,
                                                float* __restrict__ acc,
                                                int* __restrict__ counter) {
    __shared__ __align__(16) float Es[64 * 256];   // 64 rows x 1KB
    __shared__ int sidx[64];
    __shared__ float wred[4];
    const int t = threadIdx.x;
    const int b = blockIdx.x >> 4, ht = blockIdx.x & 15;

    if (t < 64) sidx[t] = idxw[b * 1024 + ht * 64 + t];
    __syncthreads();
    const float4* E4 = (const float4*)E;
    #pragma unroll
    for (int r = 0; r < 16; ++r) {
        int li = r * 256 + t;
        int row = li >> 6, slot = li & 63;
        float4 v = E4[(size_t)sidx[row] * 64 + slot];
        *(float4*)&Es[row * 256 + ((slot ^ (row & 15)) * 4)] = v;
    }
    __syncthreads();

    const int hw = t & 63, wv = t >> 6;
    float s = 0.0f;
    #pragma unroll 8
    for (int cc = 0; cc < 64; ++cc) {
        int c = wv * 64 + cc;
        float e = Es[hw * 256 + (((c >> 2) ^ (hw & 15)) * 4) + (c & 3)];
        size_t gi = (size_t)(b * 256 + c) * 1024 + ht * 64 + hw;
        float zv = zg[gi];
        out[gi] = e;
        float d = e - zv;
        s = fmaf(d, d, s);
    }
    #pragma unroll
    for (int off = 32; off > 0; off >>= 1) s += __shfl_down(s, off, 64);
    if ((t & 63) == 0) wred[wv] = s;
    __syncthreads();
    if (t == 0) {
        atomicAdd(acc, wred[0] + wred[1] + wred[2] + wred[3]);
        __threadfence();
        int old = atomicAdd(counter, 1);
        if (old == 511) {
            float total = atomicAdd(acc, 0.0f);   // RMW => device-coherent read
            float mse = total / 8388608.0f;
            out[OUT_LOSS + 0] = 1.25f * mse;
            out[OUT_LOSS + 1] = 0.25f * mse;
            out[OUT_LOSS + 2] = mse;
        }
    }
}

extern "C" void kernel_launch(void* const* d_in, const int* in_sizes, int n_in,
                              void* d_out, int out_size, void* d_ws, size_t ws_size,
                              hipStream_t stream) {
    const float* zg = (const float*)d_in[0];
    const float* E  = (const float*)d_in[1];
    float* out = (float*)d_out;
    float* wsf = (float*)d_ws;
    float*  acc     = wsf;
    int*    counter = (int*)(wsf + 1);
    float*  en      = wsf + 64;
    int*    idxw    = (int*)(wsf + 64 + NK);
    float2* part2   = (float2*)(wsf + 64 + NK + NTOK);            // 8 MB used
    unsigned short* Epre = (unsigned short*)(wsf + 64 + NK + NTOK + 4194304);  // 4 MB
    unsigned short* Zpre = (unsigned short*)d_out;                // 16 MB scratch

    k_cast  <<<3072, 256, 0, stream>>>(zg, E, Epre, Zpre, en, acc, counter);
    k_dist  <<<dim3(32, 256), 512, 0, stream>>>(Epre, Zpre, en, part2);
    k_refine<<<NTOK / 64, 256, 0, stream>>>(zg, E, part2, idxw, out);
    k_gather<<<512, 256, 0, stream>>>(E, zg, idxw, out, acc, counter);
}

// Round 9
// 282.055 us; speedup vs baseline: 1.0633x; 1.0620x over previous
//
#include <hip/hip_runtime.h>
#include <float.h>

// Problem constants
#define NBATCH 32
#define NCHAN  256
#define NHW    1024          // 32*32
#define NTOK   32768         // NBATCH * NHW
#define NK     8192          // codebook size
#define ND     256           // token dim
#define ZELEMS 8388608       // NBATCH*NCHAN*NHW
#define OUT_LOSS 8388608
#define OUT_IDX  8388611
#define MARGIN   1.2e-4f     // bf16 pre-screen err + fp32 quant tie window + slack

typedef short bf16x8  __attribute__((ext_vector_type(8)));
typedef float f32x4   __attribute__((ext_vector_type(4)));
typedef float f32x16  __attribute__((ext_vector_type(16)));

__device__ __forceinline__ unsigned short f2bf(float f) {   // RNE
    unsigned int u = __float_as_uint(f);
    u += 0x7FFFu + ((u >> 16) & 1u);
    return (unsigned short)(u >> 16);
}

__device__ __forceinline__ float embed8(float x, int code) {
    return __int_as_float((__float_as_int(x) & 0xFFFFFF00) | code);
}

// ws layout (floats):
//  [0..1] loss accumulator (double), [2] block counter (int)
//  [64 .. 64+8192)        en[k] = ||e_k||^2
//  [8256 .. +32768)       idxw (int) per token
//  [41024 .. +4194304)    part2: float2 [32 slot][32768 tok] (8 MB used)
//  then                   Epre: bf16 E [64 tile][8 kc][4 plane][128 row][16B] (4 MB)
// Zpre (bf16 z, [256 mb][8 kc][4 plane][128 tok][16B], 16 MB) lives in
// d_out[0..16MB) until k_gather rewrites it.  plane = ks*2+lhi (K-subchunk).

// ---------------------------------------------------------------- casts
// blocks [0,1024): E -> Epre (+ en, acc/counter init); [1024,3072): z -> Zpre
__global__ __launch_bounds__(256) void k_cast(const float* __restrict__ zg,
                                              const float* __restrict__ E,
                                              unsigned short* __restrict__ Epre,
                                              unsigned short* __restrict__ Zpre,
                                              float* __restrict__ en,
                                              double* __restrict__ acc,
                                              int* __restrict__ counter) {
    __shared__ unsigned short buf[128][34];
    const int t = threadIdx.x;
    if (blockIdx.x < 1024) {
        int g = blockIdx.x * 256 + t;                // 8192 codes * 32 chunks
        int code = g >> 5, c16 = g & 31;             // c16: 16B chunk = 8 channels
        int kc = c16 >> 2, ks = (c16 >> 1) & 1, lhi = c16 & 1;
        const float4* E4 = (const float4*)(E + code * ND + c16 * 8);
        float4 a = E4[0], b = E4[1];
        float s = a.x*a.x + a.y*a.y + a.z*a.z + a.w*a.w
                + b.x*b.x + b.y*b.y + b.z*b.z + b.w*b.w;
        #pragma unroll
        for (int off = 1; off < 32; off <<= 1) s += __shfl_xor(s, off, 64);
        if ((t & 31) == 0) en[code] = s;
        unsigned int u[4];
        u[0] = (unsigned int)f2bf(a.x) | ((unsigned int)f2bf(a.y) << 16);
        u[1] = (unsigned int)f2bf(a.z) | ((unsigned int)f2bf(a.w) << 16);
        u[2] = (unsigned int)f2bf(b.x) | ((unsigned int)f2bf(b.y) << 16);
        u[3] = (unsigned int)f2bf(b.z) | ((unsigned int)f2bf(b.w) << 16);
        *(uint4*)((char*)Epre + (size_t)(code >> 7) * 65536 + kc * 8192
                  + (ks * 2 + lhi) * 2048 + (code & 127) * 16) =
            make_uint4(u[0], u[1], u[2], u[3]);
        if (blockIdx.x == 0 && t == 0) { acc[0] = 0.0; counter[0] = 0; }
    } else {
        int bi = blockIdx.x - 1024;           // 32 b * 8 kc * 8 hwt
        int b = bi >> 6, kc = (bi >> 3) & 7, hwt = bi & 7;
        int c0 = kc * 32, hw0 = hwt * 128;
        #pragma unroll
        for (int r = 0; r < 4; ++r) {
            int idx = r * 256 + t;
            int c = idx >> 5, q = idx & 31;
            float4 v = *(const float4*)&zg[(b * 256 + c0 + c) * 1024 + hw0 + q * 4];
            buf[q * 4 + 0][c] = f2bf(v.x);
            buf[q * 4 + 1][c] = f2bf(v.y);
            buf[q * 4 + 2][c] = f2bf(v.z);
            buf[q * 4 + 3][c] = f2bf(v.w);
        }
        __syncthreads();
        int tok = t >> 1, ks = t & 1;
        char* base = (char*)Zpre + (size_t)((b * 8 + hwt) * 8 + kc) * 8192;
        #pragma unroll
        for (int lhi = 0; lhi < 2; ++lhi) {
            unsigned int u[4];
            #pragma unroll
            for (int k = 0; k < 4; ++k) {
                int cc = ks * 16 + lhi * 8 + 2 * k;
                u[k] = (unsigned int)buf[tok][cc] | ((unsigned int)buf[tok][cc + 1] << 16);
            }
            *(uint4*)(base + (ks * 2 + lhi) * 2048 + tok * 16) =
                make_uint4(u[0], u[1], u[2], u[3]);
        }
    }
}

// ---------------------------------------------------------------- kernel 2
// MFMA pre-screen, D[code][token], 32x32x16 bf16.
// R9: R4 tiling (256x128 block, 4 waves of 128x64, 3 LDS buffers, counted
// vmcnt) + the m201 DUAL-BARRIER PHASE LOCK that every prior null variant
// lacked: per kc {ds_read frags; lgkmcnt(0); BARRIER-R; STAGE(kc+2);
// setprio(1) MFMA x16 setprio(0); vmcnt(N); BARRIER-M}. All waves alternate
// LDS-phase and MFMA-phase coherently instead of drifting (the m196/m218
// measured lever, +28-41% on GEMM). sched_barrier(0) after BARRIER-R pins
// MFMAs from hoisting above the phase boundary.
// vmcnt ledger (en(1), S0(6), S1(6) pre-loop; S_{kc+2}(6) at kc<6):
//   prologue vmcnt(6): buf0 landed. BARRIER-M(kc<6): vmcnt(6) -> only
//   S_{kc+2} in flight, S_{kc+1} landed for next reads. kc=6: vmcnt(0)
//   (S7 landed). kc=7: no trailing wait (epilogue __syncthreads drains).
// Overwrite safety: STAGE at kc writes buf (kc-1)%3, whose reads were
// sealed by lgkmcnt(0)+BARRIER-R at kc-1 (two barriers earlier).
__global__ __launch_bounds__(256, 2) void k_dist(const unsigned short* __restrict__ Epre,
                                                 const unsigned short* __restrict__ Zpre,
                                                 const float* __restrict__ en,
                                                 float2* __restrict__ part2) {
    __shared__ __align__(16) char Elds[3][16384];   // 3buf: 2 subtile x 4 plane x 128 row x 16B
    __shared__ __align__(16) char Zlds[3][8192];    // 3buf: 4 plane x 128 tok x 16B
    __shared__ float2 red[2][128];
    __shared__ float en_s[256];

    const int t    = threadIdx.x;
    const int kbb2 = blockIdx.x;               // 0..31 (256 codes each)
    const int mb   = blockIdx.y;               // 0..255
    const int n0   = mb * 128;
    const int w    = t >> 6, lane = t & 63;
    const int l31  = lane & 31, lhi = lane >> 5;
    const int wm   = w >> 1, wn = w & 1;       // wave tile: 128 codes x 64 tokens

    const char* Esrc = (const char*)Epre + (size_t)kbb2 * 131072;  // 2 tiles
    const char* Zsrc = (const char*)Zpre + (size_t)mb * 65536;

    auto STAGE = [&](int bb, int kc) {         // 6 glls per thread (256 thr)
        #pragma unroll
        for (int s2 = 0; s2 < 2; ++s2)
            #pragma unroll
            for (int h = 0; h < 2; ++h)
                __builtin_amdgcn_global_load_lds(
                    (const unsigned int*)(Esrc + (size_t)s2 * 65536 + kc * 8192 + h * 4096 + t * 16),
                    (unsigned int*)&Elds[bb][s2 * 8192 + h * 4096 + t * 16], 16, 0, 0);
        #pragma unroll
        for (int h = 0; h < 2; ++h)
            __builtin_amdgcn_global_load_lds(
                (const unsigned int*)(Zsrc + kc * 8192 + h * 4096 + t * 16),
                (unsigned int*)&Zlds[bb][h * 4096 + t * 16], 16, 0, 0);
    };

    f32x16 acc[4][2];                          // [i][j]
    #pragma unroll
    for (int i = 0; i < 4; ++i)
        #pragma unroll
        for (int j = 0; j < 2; ++j) acc[i][j] = (f32x16)0.0f;

    float en_v = en[kbb2 * 256 + t];
    STAGE(0, 0);
    STAGE(1, 1);
    asm volatile("s_waitcnt vmcnt(6)" ::: "memory");   // buf0 landed (en position-robust)
    __builtin_amdgcn_s_barrier();

    const int eoff = wm * 8192 + lhi * 2048 + l31 * 16;
    const int zoff = lhi * 2048 + (wn * 64 + l31) * 16;

    #pragma unroll
    for (int kc = 0; kc < 8; ++kc) {
        const int pp = kc % 3;
        // ---- LDS phase ----
        const char* Eb = &Elds[pp][0] + eoff;
        const char* Zb = &Zlds[pp][0] + zoff;
        bf16x8 ea[4][2], zb[2][2];
        #pragma unroll
        for (int i = 0; i < 4; ++i)
            #pragma unroll
            for (int ks = 0; ks < 2; ++ks)
                ea[i][ks] = *(const bf16x8*)(Eb + ks * 4096 + i * 512);
        #pragma unroll
        for (int j = 0; j < 2; ++j)
            #pragma unroll
            for (int ks = 0; ks < 2; ++ks)
                zb[j][ks] = *(const bf16x8*)(Zb + ks * 4096 + j * 512);
        asm volatile("s_waitcnt lgkmcnt(0)" ::: "memory");  // seal this buf's reads
        __builtin_amdgcn_s_barrier();                       // BARRIER-R
        __builtin_amdgcn_sched_barrier(0);                  // pin phase boundary
        if (kc < 6) STAGE((kc + 2) % 3, kc + 2);            // overwrite (kc-1)%3: sealed

        // ---- MFMA phase ----
        __builtin_amdgcn_s_setprio(1);
        #pragma unroll
        for (int ks = 0; ks < 2; ++ks)
            #pragma unroll
            for (int i = 0; i < 4; ++i)
                #pragma unroll
                for (int j = 0; j < 2; ++j)
                    acc[i][j] = __builtin_amdgcn_mfma_f32_32x32x16_bf16(
                        ea[i][ks], zb[j][ks], acc[i][j], 0, 0, 0);
        __builtin_amdgcn_s_setprio(0);
        if (kc < 6)      { asm volatile("s_waitcnt vmcnt(6)" ::: "memory"); __builtin_amdgcn_s_barrier(); }
        else if (kc == 6){ asm volatile("s_waitcnt vmcnt(0)" ::: "memory"); __builtin_amdgcn_s_barrier(); }
        // kc==7: falls through to epilogue __syncthreads
    }

    en_s[t] = en_v;
    __syncthreads();                           // full drain before epilogue

    // ---- epilogue: per-token top-2 smallest s = en - 2*dot, 8-bit embed ----
    // 4 independent chains (per i) for ILP, merged pairwise at the end.
    float v1[2][4], v2[2][4];
    #pragma unroll
    for (int j = 0; j < 2; ++j)
        #pragma unroll
        for (int i = 0; i < 4; ++i) { v1[j][i] = FLT_MAX; v2[j][i] = FLT_MAX; }
    #pragma unroll
    for (int i = 0; i < 4; ++i) {
        const int cb = wm * 128 + i * 32 + lhi * 4;
        #pragma unroll
        for (int rq = 0; rq < 4; ++rq) {
            f32x4 ev = *(const f32x4*)&en_s[cb + 8 * rq];
            #pragma unroll
            for (int rr = 0; rr < 4; ++rr) {
                const int r = rq * 4 + rr;
                const int code = cb + 8 * rq + rr;       // 0..255 local
                #pragma unroll
                for (int j = 0; j < 2; ++j) {
                    float s  = fmaf(-2.0f, acc[i][j][r], ev[rr]);
                    float se = embed8(s, code);
                    v2[j][i] = __builtin_amdgcn_fmed3f(se, v1[j][i], v2[j][i]);
                    v1[j][i] = fminf(v1[j][i], se);
                }
            }
        }
    }
    // merge 4 sorted pairs -> 1 (per j): (lo,hi) merge = min/max/min/min
    float m1[2], m2[2];
    #pragma unroll
    for (int j = 0; j < 2; ++j) {
        float a1 = fminf(v1[j][0], v1[j][1]);
        float ah = fmaxf(v1[j][0], v1[j][1]);
        float a2 = fminf(ah, fminf(v2[j][0], v2[j][1]));
        float b1 = fminf(v1[j][2], v1[j][3]);
        float bh = fmaxf(v1[j][2], v1[j][3]);
        float b2 = fminf(bh, fminf(v2[j][2], v2[j][3]));
        m1[j] = fminf(a1, b1);
        m2[j] = fminf(fmaxf(a1, b1), fminf(a2, b2));
    }
    #pragma unroll
    for (int j = 0; j < 2; ++j) {              // merge lhi partner (xor 32)
        float b1 = __shfl_xor(m1[j], 32, 64);
        float b2 = __shfl_xor(m2[j], 32, 64);
        float hi = fmaxf(m1[j], b1);
        m1[j] = fminf(m1[j], b1);
        m2[j] = fminf(fminf(hi, m2[j]), b2);
    }
    if (lane < 32) {
        #pragma unroll
        for (int j = 0; j < 2; ++j)
            red[wm][wn * 64 + j * 32 + l31] = make_float2(m1[j], m2[j]);
    }
    __syncthreads();
    if (t < 128) {
        float2 A = red[0][t], B = red[1][t];
        float g1 = fminf(A.x, B.x);
        float g2 = fminf(fminf(fmaxf(A.x, B.x), A.y), B.y);
        // slot-major: 128 consecutive float2 per block = 1KB full lines
        part2[(size_t)kbb2 * NTOK + n0 + t] = make_float2(g1, g2);
    }
}

// ---------------------------------------------------------------- kernel 3
// Refine: block stages z for 64 tokens into LDS (coalesced); per token-wave,
// mimic reference fp32 rounding:
//   d_q(k) = fl32( z2f - fl32(2*<z,e_k>_fp64) ), argmin, first-index ties.
// 32 slots per token (256 codes each), 8-bit embedded local index.
// R9: loss fused here via f64 identity  sum_c (e_c - z_c)^2
//     = en[idx] - 2*<z,e> + ||z||^2  (en fp32 ~1e-13 abs err; g,z2 f64).
// k_gather no longer reads z or reduces loss.
__global__ __launch_bounds__(256) void k_refine(const float* __restrict__ zg,
                                                const float* __restrict__ E,
                                                const float* __restrict__ en,
                                                const float2* __restrict__ part2,
                                                int* __restrict__ idxw,
                                                float* __restrict__ outF,
                                                double* __restrict__ acc,
                                                int* __restrict__ counter) {
    __shared__ float Zs[256 * 65];             // [c][tok] stride 65 (bank-clean)
    __shared__ double lred[4];
    const int t = threadIdx.x;
    const int n0 = blockIdx.x * 64;
    const int b = n0 >> 10, hw0 = n0 & 1023;

    #pragma unroll
    for (int r = 0; r < 16; ++r) {
        int li = r * 256 + t;
        int c = li >> 4, q = li & 15;
        float4 v = *(const float4*)&zg[(b * 256 + c) * 1024 + hw0 + q * 4];
        Zs[c * 65 + q * 4 + 0] = v.x;
        Zs[c * 65 + q * 4 + 1] = v.y;
        Zs[c * 65 + q * 4 + 2] = v.z;
        Zs[c * 65 + q * 4 + 3] = v.w;
    }
    __syncthreads();

    const int w = t >> 6, l = t & 63;
    double lsum = 0.0;
    for (int it = 0; it < 16; ++it) {
        const int tokl = w * 16 + it;
        const int n = n0 + tokl;

        float zreg[4];
        #pragma unroll
        for (int j = 0; j < 4; ++j) zreg[j] = Zs[(64 * j + l) * 65 + tokl];

        double z2 = 0.0;
        #pragma unroll
        for (int j = 0; j < 4; ++j) z2 += (double)zreg[j] * (double)zreg[j];
        #pragma unroll
        for (int m = 1; m < 64; m <<= 1) z2 += __shfl_xor(z2, m, 64);
        const float z2f = (float)z2;

        float2 p = make_float2(FLT_MAX, FLT_MAX);
        if (l < 32) p = part2[(size_t)l * NTOK + n];   // slot-major, 32 slots
        int code1 = (l << 8) | (__float_as_int(p.x) & 0xFF);
        int code2 = (l << 8) | (__float_as_int(p.y) & 0xFF);

        float vmin = p.x;
        #pragma unroll
        for (int m = 1; m < 64; m <<= 1) vmin = fminf(vmin, __shfl_xor(vmin, m, 64));
        const float thr = vmin + MARGIN;

        unsigned long long m1 = __ballot(p.x <= thr);
        unsigned long long m2 = __ballot(p.y <= thr);

        float bdq = FLT_MAX; int bidx = 0x7fffffff; double gw = 0.0;
        #pragma unroll
        for (int pass = 0; pass < 2; ++pass) {
            unsigned long long mm = pass ? m2 : m1;
            int ibits = pass ? code2 : code1;
            while (mm) {
                int src = __ffsll(mm) - 1; mm &= mm - 1;
                int cidx = __shfl(ibits, src, 64);
                const float* erow = E + cidx * ND;
                double g = (double)zreg[0] * (double)erow[l]
                         + (double)zreg[1] * (double)erow[64 + l]
                         + (double)zreg[2] * (double)erow[128 + l]
                         + (double)zreg[3] * (double)erow[192 + l];
                #pragma unroll
                for (int mk = 1; mk < 64; mk <<= 1) g += __shfl_xor(g, mk, 64);
                float c  = (float)(2.0 * g);
                float dq = z2f - c;
                if (dq < bdq || (dq == bdq && cidx < bidx)) { bdq = dq; bidx = cidx; gw = g; }
            }
        }
        if (l == 0) {
            idxw[n] = bidx; outF[OUT_IDX + n] = (float)bidx;
            lsum += (double)en[bidx] - 2.0 * gw + z2;   // sum_c (e-z)^2 exact-f64
        }
    }
    if (l == 0) lred[w] = lsum;
    __syncthreads();
    if (t == 0) {
        atomicAdd(acc, lred[0] + lred[1] + lred[2] + lred[3]);
        __threadfence();
        int old = atomicAdd(counter, 1);
        if (old == 511) {
            double total = atomicAdd(acc, 0.0);   // RMW => device-coherent read
            double mse = total / 8388608.0;
            outF[OUT_LOSS + 0] = (float)(1.25 * mse);
            outF[OUT_LOSS + 1] = (float)(0.25 * mse);
            outF[OUT_LOSS + 2] = (float)mse;
        }
    }
}

// ---------------------------------------------------------------- kernel 4
// Pure gather via LDS-staged E rows (coalesced 1KB row loads, XOR-swizzled).
// R9: loss moved to k_refine -> no z read, no reduction here.
__global__ __launch_bounds__(256) void k_gather(const float* __restrict__ E,
                                                const int* __restrict__ idxw,
                                                float* __restrict__ out) {
    __shared__ __align__(16) float Es[64 * 256];   // 64 rows x 1KB
    __shared__ int sidx[64];
    const int t = threadIdx.x;
    const int b = blockIdx.x >> 4, ht = blockIdx.x & 15;

    if (t < 64) sidx[t] = idxw[b * 1024 + ht * 64 + t];
    __syncthreads();
    const float4* E4 = (const float4*)E;
    #pragma unroll
    for (int r = 0; r < 16; ++r) {
        int li = r * 256 + t;
        int row = li >> 6, slot = li & 63;
        float4 v = E4[(size_t)sidx[row] * 64 + slot];
        *(float4*)&Es[row * 256 + ((slot ^ (row & 15)) * 4)] = v;
    }
    __syncthreads();

    const int hw = t & 63, wv = t >> 6;
    #pragma unroll 8
    for (int cc = 0; cc < 64; ++cc) {
        int c = wv * 64 + cc;
        float e = Es[hw * 256 + (((c >> 2) ^ (hw & 15)) * 4) + (c & 3)];
        size_t gi = (size_t)(b * 256 + c) * 1024 + ht * 64 + hw;
        out[gi] = e;
    }
}

extern "C" void kernel_launch(void* const* d_in, const int* in_sizes, int n_in,
                              void* d_out, int out_size, void* d_ws, size_t ws_size,
                              hipStream_t stream) {
    const float* zg = (const float*)d_in[0];
    const float* E  = (const float*)d_in[1];
    float* out = (float*)d_out;
    float* wsf = (float*)d_ws;
    double* acc     = (double*)wsf;                                // wsf[0..1]
    int*    counter = (int*)(wsf + 2);
    float*  en      = wsf + 64;
    int*    idxw    = (int*)(wsf + 64 + NK);
    float2* part2   = (float2*)(wsf + 64 + NK + NTOK);            // 8 MB used
    unsigned short* Epre = (unsigned short*)(wsf + 64 + NK + NTOK + 4194304);  // 4 MB
    unsigned short* Zpre = (unsigned short*)d_out;                // 16 MB scratch

    k_cast  <<<3072, 256, 0, stream>>>(zg, E, Epre, Zpre, en, acc, counter);
    k_dist  <<<dim3(32, 256), 256, 0, stream>>>(Epre, Zpre, en, part2);
    k_refine<<<NTOK / 64, 256, 0, stream>>>(zg, E, en, part2, idxw, out, acc, counter);
    k_gather<<<512, 256, 0, stream>>>(E, idxw, out);
}